// Round 24
// baseline (76.273 us; speedup 1.0000x reference)
//
#include <hip/hip_runtime.h>

#define BTOT 65536
#define TST  28
#define PACK_DW 180
// ws layout (dwords): [0 .. 11520) packed frags (64 lanes x 180)
//                     [11520 .. 15616) WxL: 32 x 128 f32 (rows 29..31 zeroed)
#define WXL_OFF (64 * PACK_DW)

typedef __attribute__((ext_vector_type(8))) short bf16x8;
typedef __attribute__((ext_vector_type(4))) float f32x4;

__device__ __forceinline__ unsigned int f2bf(float f) {
    unsigned u = __float_as_uint(f);
    u += 0x7fff + ((u >> 16) & 1);   // RNE
    return u >> 16;
}
__device__ __forceinline__ unsigned int pk2bf(float a, float b) {
    return f2bf(a) | (f2bf(b) << 16);
}
__device__ __forceinline__ bf16x8 cvt8(f32x4 a, f32x4 b) {
    union { unsigned int u[4]; bf16x8 v; } r;
    asm("v_cvt_pk_bf16_f32 %0, %1, %2" : "=v"(r.u[0]) : "v"(a[0]), "v"(a[1]));
    asm("v_cvt_pk_bf16_f32 %0, %1, %2" : "=v"(r.u[1]) : "v"(a[2]), "v"(a[3]));
    asm("v_cvt_pk_bf16_f32 %0, %1, %2" : "=v"(r.u[2]) : "v"(b[0]), "v"(b[1]));
    asm("v_cvt_pk_bf16_f32 %0, %1, %2" : "=v"(r.u[3]) : "v"(b[2]), "v"(b[3]));
    return r.v;
}

// HIDDEN-UNIT PERMUTATION sigma: B-frag slot (kh,kk,jd,b) consumes logical
// unit s = kk*32 + (jd>>1)*16 + kh*4 + (jd&1)*2 + b. With W2b/W3 input-rows
// packed by sigma, the cvt_pk dwords of acc tiles (2kk,2kk+1) ARE hb[kk] at
// the same lane -> h feedback is register-only (zero LDS). Verified r23.

// pack1: blocks 0..28 compute WxL row k (Wx = W1@W2a; row 28 = b2 + b1@W2a, hit
// by x-frag element k=28 := 1.0; block 28 zeroes rows 29..31). Block 29 packs
// W2b A-frags with sigma on the input-row index; block 30 packs W3 frags
// (sigma on rows) + b3 D-init.
// Per-lane dword layout: [0..128) w2b(kk,t8) | [128..160) wx(t8)
//                        [160..176) w3(kk)   | [176..180) b3 (f32, D rows)
__global__ void pack1(const float* __restrict__ W1, const float* __restrict__ b1,
                      const float* __restrict__ W2, const float* __restrict__ b2,
                      const float* __restrict__ W3, const float* __restrict__ b3,
                      unsigned int* __restrict__ ws) {
    float* WxL = (float*)(ws + WXL_OFF);
    const int bid = blockIdx.x, tid = threadIdx.x;
    if (bid < 29) {
        const int k = bid, n = tid;   // 128 threads
        float s = 0.f;
        if (k < 28) {
            for (int m = 0; m < 128; ++m) s += W1[k * 128 + m] * W2[m * 128 + n];
        } else {
            s = b2[n];
            for (int m = 0; m < 128; ++m) s += b1[m] * W2[m * 128 + n];
        }
        WxL[k * 128 + n] = s;
        if (k == 28) { WxL[29*128+n] = 0.f; WxL[30*128+n] = 0.f; WxL[31*128+n] = 0.f; }
    } else if (bid == 29) {
        if (tid < 64) {
            const int lr = tid & 15, kh = tid >> 4;
            unsigned int* P = ws + tid * PACK_DW;
            for (int kk = 0; kk < 4; ++kk)
                for (int t8 = 0; t8 < 8; ++t8)
                    for (int jd = 0; jd < 4; ++jd) {
                        const int s = kk * 32 + (jd >> 1) * 16 + kh * 4 + (jd & 1) * 2;
                        const int n = t8 * 16 + lr;
                        P[(kk * 8 + t8) * 4 + jd] =
                            pk2bf(W2[(128 + s) * 128 + n], W2[(129 + s) * 128 + n]);
                    }
        }
    } else {
        if (tid < 64) {
            const int lr = tid & 15, kh = tid >> 4;
            unsigned int* P = ws + tid * PACK_DW;
            for (int kk = 0; kk < 4; ++kk)
                for (int jd = 0; jd < 4; ++jd) {
                    const int s = kk * 32 + (jd >> 1) * 16 + kh * 4 + (jd & 1) * 2;
                    float lo = (lr < 10) ? W3[s * 10 + lr] : 0.f;
                    float hi = (lr < 10) ? W3[(s + 1) * 10 + lr] : 0.f;
                    P[160 + kk * 4 + jd] = pk2bf(lo, hi);
                }
            for (int j = 0; j < 4; ++j) {
                const int o = kh * 4 + j;
                P[176 + j] = __float_as_uint((o < 10) ? b3[o] : 0.f);
            }
        }
    }
}

// pack2: Wx A-frags (x's k-dimension — sigma does not apply).
__global__ void pack2(unsigned int* __restrict__ ws) {
    const int tid = threadIdx.x;
    if (tid < 64) {
        const float* WxL = (const float*)(ws + WXL_OFF);
        const int lr = tid & 15, kh = tid >> 4;
        unsigned int* P = ws + tid * PACK_DW;
        for (int t8 = 0; t8 < 8; ++t8)
            for (int jd = 0; jd < 4; ++jd) {
                const int k = kh * 8 + jd * 2, n = t8 * 16 + lr;
                P[128 + t8 * 4 + jd] = pk2bf(WxL[k * 128 + n], WxL[(k + 1) * 128 + n]);
            }
    }
}

#define MFMA(a, b, c) __builtin_amdgcn_mfma_f32_16x16x32_bf16(a, b, c, 0, 0, 0)

// ZERO-LDS recurrence (r23, 71.9us) with a ROTATED, tail-overlapped schedule:
// step body = [32 h-MFMAs into acc (which already holds the x-part)] then
// interleaved [CVT 2 tiles -> 2 NEXT-step x-MFMAs into the freed acc regs] x4.
// The x-MFMAs are independent of hb, so the MFMA pipe has work during the CVT
// window, and the next h-cluster starts immediately after the last CVT pair.
// Fully unrolled (27 iters ~ fits L1I) so scheduling crosses step boundaries.
__global__ __launch_bounds__(64, 2) void rnn_kernel(
    const float* __restrict__ x, const unsigned int* __restrict__ wsPack,
    float* __restrict__ out)
{
    const int lane = threadIdx.x;
    const int lr = lane & 15, kh = lane >> 4;
    const int r0 = blockIdx.x * 16;

    const unsigned int* P = wsPack + lane * PACK_DW;
    bf16x8 w2b[4][8], wx[8];
    #pragma unroll
    for (int kk = 0; kk < 4; ++kk)
        #pragma unroll
        for (int t8 = 0; t8 < 8; ++t8)
            w2b[kk][t8] = *(const bf16x8*)(P + (kk * 8 + t8) * 4);
    #pragma unroll
    for (int t8 = 0; t8 < 8; ++t8) wx[t8] = *(const bf16x8*)(P + 128 + t8 * 4);

    // x B-frag: lane (kh,lr) covers k = 8kh + j of x[r0+lr][28t + k];
    // kh==3 upper half = {1.0 (k=28 bias hook), 0, 0, 0} — Wx rows 29..31 zero.
    const f32x4 onec = {1.f, 0.f, 0.f, 0.f};
    const float* xr = x + (size_t)(r0 + lr) * 784 + 8 * kh;
    f32x4 xa = *(const f32x4*)xr;
    f32x4 xc = (kh < 3) ? *(const f32x4*)(xr + 4) : onec;
    bf16x8 xb = cvt8(xa, xc);
    const f32x4 z4 = {0.f, 0.f, 0.f, 0.f};

    f32x4 acc[8];
    union HF { unsigned int u[4]; bf16x8 v; } hb[4];
    f32x4 na, nc;

// relu + pack acc[T8] -> the two dwords of hb[T8>>1] at offset (T8&1)*2.
#define CVT(T8) do {                                                        \
        f32x4 v = acc[T8];                                                  \
        v[0] = fmaxf(v[0], 0.f); v[1] = fmaxf(v[1], 0.f);                   \
        v[2] = fmaxf(v[2], 0.f); v[3] = fmaxf(v[3], 0.f);                   \
        unsigned lo, hi;                                                    \
        asm("v_cvt_pk_bf16_f32 %0, %1, %2" : "=v"(lo) : "v"(v[0]), "v"(v[1])); \
        asm("v_cvt_pk_bf16_f32 %0, %1, %2" : "=v"(hi) : "v"(v[2]), "v"(v[3])); \
        hb[(T8) >> 1].u[((T8) & 1) * 2]     = lo;                           \
        hb[(T8) >> 1].u[((T8) & 1) * 2 + 1] = hi;                           \
    } while (0)
// CVT pair (2t, 2t+1) then immediately refill those acc regs with the NEXT
// step's x-part (independent of hb -> MFMA pipe stays fed through the tail).
#define CVT_REFILL(PAIR) do {                                               \
        CVT(2 * (PAIR)); CVT(2 * (PAIR) + 1);                               \
        acc[2 * (PAIR)]     = MFMA(wx[2 * (PAIR)],     xb, z4);             \
        acc[2 * (PAIR) + 1] = MFMA(wx[2 * (PAIR) + 1], xb, z4);             \
    } while (0)

    // ---- prologue (step 0): h0 == 0, x part only (exact); CVT; refill with
    // step 1's x-part so the main loop starts at the h-cluster ----
    {
        const float* xp = xr + 28;
        na = *(const f32x4*)xp;
        nc = (kh < 3) ? *(const f32x4*)(xp + 4) : onec;
        #pragma unroll
        for (int t8 = 0; t8 < 8; ++t8)
            acc[t8] = MFMA(wx[t8], xb, z4);
        xb = cvt8(na, nc);   // x_1
        CVT(0); CVT(1); CVT(2); CVT(3); CVT(4); CVT(5); CVT(6); CVT(7);
        #pragma unroll
        for (int t8 = 0; t8 < 8; ++t8)
            acc[t8] = MFMA(wx[t8], xb, z4);   // step-1 x-part
    }

    // ---- steps 1..27 (fully unrolled): h-cluster, then CVT/x-refill tail ----
    #pragma unroll
    for (int t = 1; t < TST; ++t) {
        // issue x_{t+1} load early; consumed before the tail below
        const bool pf = (t + 1 < TST);
        if (pf) {
            const float* xp = xr + (t + 1) * 28;
            na = *(const f32x4*)xp;
            nc = (kh < 3) ? *(const f32x4*)(xp + 4) : onec;
        }
        __builtin_amdgcn_s_setprio(1);
        #pragma unroll
        for (int kk = 0; kk < 4; ++kk)
            #pragma unroll
            for (int t8 = 0; t8 < 8; ++t8)
                acc[t8] = MFMA(w2b[kk][t8], hb[kk].v, acc[t8]);
        __builtin_amdgcn_s_setprio(0);
        if (pf) {
            xb = cvt8(na, nc);   // x_{t+1} frag for the refill below
            CVT_REFILL(0); CVT_REFILL(1); CVT_REFILL(2); CVT_REFILL(3);
        } else {
            CVT(0); CVT(1); CVT(2); CVT(3); CVT(4); CVT(5); CVT(6); CVT(7);
        }
    }

    // epilogue: out^T = W3^T . h_final^T + b3 — hb holds h_final
    bf16x8 w3f[4];
    #pragma unroll
    for (int kk = 0; kk < 4; ++kk) w3f[kk] = *(const bf16x8*)(P + 160 + kk * 4);
    const float* bp = (const float*)(P + 176);
    f32x4 accO = {bp[0], bp[1], bp[2], bp[3]};
    #pragma unroll
    for (int kk = 0; kk < 4; ++kk)
        accO = MFMA(w3f[kk], hb[kk].v, accO);
    float* op = out + (size_t)(r0 + lr) * 10 + kh * 4;
    #pragma unroll
    for (int j = 0; j < 4; ++j)
        if (kh * 4 + j < 10) op[j] = accO[j];

#undef CVT
#undef CVT_REFILL
}

extern "C" void kernel_launch(void* const* d_in, const int* in_sizes, int n_in,
                              void* d_out, int out_size, void* d_ws, size_t ws_size,
                              hipStream_t stream) {
    const float* x  = (const float*)d_in[0];
    const float* W1 = (const float*)d_in[1];
    const float* b1 = (const float*)d_in[2];
    const float* W2 = (const float*)d_in[3];
    const float* b2 = (const float*)d_in[4];
    const float* W3 = (const float*)d_in[5];
    const float* b3 = (const float*)d_in[6];
    unsigned int* ws = (unsigned int*)d_ws;   // 15616 dwords = 61 KiB

    pack1<<<31, 128, 0, stream>>>(W1, b1, W2, b2, W3, b3, ws);
    pack2<<<1, 64, 0, stream>>>(ws);
    rnn_kernel<<<BTOT / 16, 64, 0, stream>>>(x, ws, (float*)d_out);
}

// Round 25
// 72.991 us; speedup vs baseline: 1.0450x; 1.0450x over previous
//
#include <hip/hip_runtime.h>

#define BTOT 65536
#define TST  28
#define PACK_DW 180
// ws layout (dwords): [0 .. 11520) packed frags (64 lanes x 180)
//                     [11520 .. 15616) WxL: 32 x 128 f32 (rows 29..31 zeroed)
#define WXL_OFF (64 * PACK_DW)

typedef __attribute__((ext_vector_type(8))) short bf16x8;
typedef __attribute__((ext_vector_type(4))) float f32x4;

__device__ __forceinline__ unsigned int f2bf(float f) {
    unsigned u = __float_as_uint(f);
    u += 0x7fff + ((u >> 16) & 1);   // RNE
    return u >> 16;
}
__device__ __forceinline__ unsigned int pk2bf(float a, float b) {
    return f2bf(a) | (f2bf(b) << 16);
}
__device__ __forceinline__ bf16x8 cvt8(f32x4 a, f32x4 b) {
    union { unsigned int u[4]; bf16x8 v; } r;
    asm("v_cvt_pk_bf16_f32 %0, %1, %2" : "=v"(r.u[0]) : "v"(a[0]), "v"(a[1]));
    asm("v_cvt_pk_bf16_f32 %0, %1, %2" : "=v"(r.u[1]) : "v"(a[2]), "v"(a[3]));
    asm("v_cvt_pk_bf16_f32 %0, %1, %2" : "=v"(r.u[2]) : "v"(b[0]), "v"(b[1]));
    asm("v_cvt_pk_bf16_f32 %0, %1, %2" : "=v"(r.u[3]) : "v"(b[2]), "v"(b[3]));
    return r.v;
}

// HIDDEN-UNIT PERMUTATION sigma: B-frag slot (kh,kk,jd,b) consumes logical
// unit s = kk*32 + (jd>>1)*16 + kh*4 + (jd&1)*2 + b. With W2b/W3 input-rows
// packed by sigma, the cvt_pk dwords of acc tiles (2kk,2kk+1) ARE hb[kk] at
// the same lane -> h feedback is register-only (zero LDS). Verified r23.

// pack1: blocks 0..28 compute WxL row k (Wx = W1@W2a; row 28 = b2 + b1@W2a, hit
// by x-frag element k=28 := 1.0; block 28 zeroes rows 29..31). Block 29 packs
// W2b A-frags with sigma on the input-row index; block 30 packs W3 frags
// (sigma on rows) + b3 D-init.
// Per-lane dword layout: [0..128) w2b(kk,t8) | [128..160) wx(t8)
//                        [160..176) w3(kk)   | [176..180) b3 (f32, D rows)
__global__ void pack1(const float* __restrict__ W1, const float* __restrict__ b1,
                      const float* __restrict__ W2, const float* __restrict__ b2,
                      const float* __restrict__ W3, const float* __restrict__ b3,
                      unsigned int* __restrict__ ws) {
    float* WxL = (float*)(ws + WXL_OFF);
    const int bid = blockIdx.x, tid = threadIdx.x;
    if (bid < 29) {
        const int k = bid, n = tid;   // 128 threads
        float s = 0.f;
        if (k < 28) {
            for (int m = 0; m < 128; ++m) s += W1[k * 128 + m] * W2[m * 128 + n];
        } else {
            s = b2[n];
            for (int m = 0; m < 128; ++m) s += b1[m] * W2[m * 128 + n];
        }
        WxL[k * 128 + n] = s;
        if (k == 28) { WxL[29*128+n] = 0.f; WxL[30*128+n] = 0.f; WxL[31*128+n] = 0.f; }
    } else if (bid == 29) {
        if (tid < 64) {
            const int lr = tid & 15, kh = tid >> 4;
            unsigned int* P = ws + tid * PACK_DW;
            for (int kk = 0; kk < 4; ++kk)
                for (int t8 = 0; t8 < 8; ++t8)
                    for (int jd = 0; jd < 4; ++jd) {
                        const int s = kk * 32 + (jd >> 1) * 16 + kh * 4 + (jd & 1) * 2;
                        const int n = t8 * 16 + lr;
                        P[(kk * 8 + t8) * 4 + jd] =
                            pk2bf(W2[(128 + s) * 128 + n], W2[(129 + s) * 128 + n]);
                    }
        }
    } else {
        if (tid < 64) {
            const int lr = tid & 15, kh = tid >> 4;
            unsigned int* P = ws + tid * PACK_DW;
            for (int kk = 0; kk < 4; ++kk)
                for (int jd = 0; jd < 4; ++jd) {
                    const int s = kk * 32 + (jd >> 1) * 16 + kh * 4 + (jd & 1) * 2;
                    float lo = (lr < 10) ? W3[s * 10 + lr] : 0.f;
                    float hi = (lr < 10) ? W3[(s + 1) * 10 + lr] : 0.f;
                    P[160 + kk * 4 + jd] = pk2bf(lo, hi);
                }
            for (int j = 0; j < 4; ++j) {
                const int o = kh * 4 + j;
                P[176 + j] = __float_as_uint((o < 10) ? b3[o] : 0.f);
            }
        }
    }
}

// pack2: Wx A-frags (x's k-dimension — sigma does not apply).
__global__ void pack2(unsigned int* __restrict__ ws) {
    const int tid = threadIdx.x;
    if (tid < 64) {
        const float* WxL = (const float*)(ws + WXL_OFF);
        const int lr = tid & 15, kh = tid >> 4;
        unsigned int* P = ws + tid * PACK_DW;
        for (int t8 = 0; t8 < 8; ++t8)
            for (int jd = 0; jd < 4; ++jd) {
                const int k = kh * 8 + jd * 2, n = t8 * 16 + lr;
                P[128 + t8 * 4 + jd] = pk2bf(WxL[k * 128 + n], WxL[(k + 1) * 128 + n]);
            }
    }
}

// ZERO-LDS recurrence (r23 = 71.9us, best) + 2-DEEP x register queue.
// r23's x issue->use distance was ~1 step; FETCH=103MB says half the x reads
// HBM-miss (~900cy), and r20's solo-wave data showed ~3000cy/step of exposed
// memory latency. With no barriers anywhere, a 2-deep queue makes issue->use
// ~2 full steps (~6000cy) >> any miss latency. Everything else is r23 exact.
__global__ __launch_bounds__(64, 2) void rnn_kernel(
    const float* __restrict__ x, const unsigned int* __restrict__ wsPack,
    float* __restrict__ out)
{
    const int lane = threadIdx.x;
    const int lr = lane & 15, kh = lane >> 4;
    const int r0 = blockIdx.x * 16;

    const unsigned int* P = wsPack + lane * PACK_DW;
    bf16x8 w2b[4][8], wx[8];
    #pragma unroll
    for (int kk = 0; kk < 4; ++kk)
        #pragma unroll
        for (int t8 = 0; t8 < 8; ++t8)
            w2b[kk][t8] = *(const bf16x8*)(P + (kk * 8 + t8) * 4);
    #pragma unroll
    for (int t8 = 0; t8 < 8; ++t8) wx[t8] = *(const bf16x8*)(P + 128 + t8 * 4);

    // x B-frag: lane (kh,lr) covers k = 8kh + j of x[r0+lr][28t + k];
    // kh==3 upper half = {1.0 (k=28 bias hook), 0, 0, 0} — Wx rows 29..31 zero.
    const f32x4 onec = {1.f, 0.f, 0.f, 0.f};
    const float* xr = x + (size_t)(r0 + lr) * 784 + 8 * kh;
    f32x4 xa = *(const f32x4*)xr;
    f32x4 xc = (kh < 3) ? *(const f32x4*)(xr + 4) : onec;
    bf16x8 xb = cvt8(xa, xc);
    const f32x4 z4 = {0.f, 0.f, 0.f, 0.f};

    f32x4 acc[8];
    union HF { unsigned int u[4]; bf16x8 v; } hb[4];
    f32x4 na1, nc1, na2, nc2;

// relu + pack acc[T8] -> the two dwords of hb[T8>>1] at offset (T8&1)*2.
#define CVT(T8) do {                                                        \
        f32x4 v = acc[T8];                                                  \
        v[0] = fmaxf(v[0], 0.f); v[1] = fmaxf(v[1], 0.f);                   \
        v[2] = fmaxf(v[2], 0.f); v[3] = fmaxf(v[3], 0.f);                   \
        unsigned lo, hi;                                                    \
        asm("v_cvt_pk_bf16_f32 %0, %1, %2" : "=v"(lo) : "v"(v[0]), "v"(v[1])); \
        asm("v_cvt_pk_bf16_f32 %0, %1, %2" : "=v"(hi) : "v"(v[2]), "v"(v[3])); \
        hb[(T8) >> 1].u[((T8) & 1) * 2]     = lo;                           \
        hb[(T8) >> 1].u[((T8) & 1) * 2 + 1] = hi;                           \
    } while (0)
#define CVTALL  CVT(0); CVT(1); CVT(2); CVT(3); CVT(4); CVT(5); CVT(6); CVT(7)

    // prologue: x_1 into queue slot 1
    {
        const float* xp = xr + 28;
        na1 = *(const f32x4*)xp;
        nc1 = (kh < 3) ? *(const f32x4*)(xp + 4) : onec;
    }

    // ---- step 0: h0 == 0, so only the x part (exact) ----
    {
        // issue x_2 (queue slot 2)
        const float* xp = xr + 2 * 28;
        na2 = *(const f32x4*)xp;
        nc2 = (kh < 3) ? *(const f32x4*)(xp + 4) : onec;
        __builtin_amdgcn_s_setprio(1);
        #pragma unroll
        for (int t8 = 0; t8 < 8; ++t8)
            acc[t8] = __builtin_amdgcn_mfma_f32_16x16x32_bf16(wx[t8], xb, z4, 0, 0, 0);
        __builtin_amdgcn_s_setprio(0);
        xb = cvt8(na1, nc1);   // x_1 (loaded in prologue)
        na1 = na2; nc1 = nc2;
        CVTALL;
    }

    // ---- steps 1..27 ----
    #pragma unroll 2
    for (int t = 1; t < TST; ++t) {
        // issue load of x_{t+2} FIRST — ~2 full steps ahead of its use
        if (t + 2 < TST) {
            const float* xp = xr + (t + 2) * 28;
            na2 = *(const f32x4*)xp;
            nc2 = (kh < 3) ? *(const f32x4*)(xp + 4) : onec;
        }
        __builtin_amdgcn_s_setprio(1);
        #pragma unroll
        for (int t8 = 0; t8 < 8; ++t8)
            acc[t8] = __builtin_amdgcn_mfma_f32_16x16x32_bf16(wx[t8], xb, z4, 0, 0, 0);
        #pragma unroll
        for (int kk = 0; kk < 4; ++kk)
            #pragma unroll
            for (int t8 = 0; t8 < 8; ++t8)
                acc[t8] = __builtin_amdgcn_mfma_f32_16x16x32_bf16(w2b[kk][t8], hb[kk].v, acc[t8], 0, 0, 0);
        __builtin_amdgcn_s_setprio(0);
        if (t + 1 < TST) {
            xb = cvt8(na1, nc1);   // x_{t+1}: its load finished a full step ago
            na1 = na2; nc1 = nc2;
        }
        CVTALL;   // registers ARE next step's B-frags (sigma packing)
    }

    // epilogue: out^T = W3^T . h_final^T + b3 — hb holds h_final already
    bf16x8 w3f[4];
    #pragma unroll
    for (int kk = 0; kk < 4; ++kk) w3f[kk] = *(const bf16x8*)(P + 160 + kk * 4);
    const float* bp = (const float*)(P + 176);
    f32x4 accO = {bp[0], bp[1], bp[2], bp[3]};
    #pragma unroll
    for (int kk = 0; kk < 4; ++kk)
        accO = __builtin_amdgcn_mfma_f32_16x16x32_bf16(w3f[kk], hb[kk].v, accO, 0, 0, 0);
    float* op = out + (size_t)(r0 + lr) * 10 + kh * 4;
    #pragma unroll
    for (int j = 0; j < 4; ++j)
        if (kh * 4 + j < 10) op[j] = accO[j];

#undef CVT
#undef CVTALL
}

extern "C" void kernel_launch(void* const* d_in, const int* in_sizes, int n_in,
                              void* d_out, int out_size, void* d_ws, size_t ws_size,
                              hipStream_t stream) {
    const float* x  = (const float*)d_in[0];
    const float* W1 = (const float*)d_in[1];
    const float* b1 = (const float*)d_in[2];
    const float* W2 = (const float*)d_in[3];
    const float* b2 = (const float*)d_in[4];
    const float* W3 = (const float*)d_in[5];
    const float* b3 = (const float*)d_in[6];
    unsigned int* ws = (unsigned int*)d_ws;   // 15616 dwords = 61 KiB

    pack1<<<31, 128, 0, stream>>>(W1, b1, W2, b2, W3, b3, ws);
    pack2<<<1, 64, 0, stream>>>(ws);
    rnn_kernel<<<BTOT / 16, 64, 0, stream>>>(x, ws, (float*)d_out);
}